// Round 3
// baseline (2581.726 us; speedup 1.0000x reference)
//
#include <hip/hip_runtime.h>
#include <cstdint>

// ---------------------------------------------------------------------------
// LSTMdecoder: attention (emb->proj->scores->softmax->context->proj) feeding a
// 2-layer LSTM over 256 timesteps. GEMMs bf16 MFMA (fp32 acc), gate math +
// cell state fp32. Sequential part = persistent kernel, 64 merged blocks
// (each does layer0 step t AND layer1 step t-1 for its 16-batch x 16-unit
// tile), one contention-free distributed barrier per phase. All weights
// register-resident (192 VGPRs). h crosses blocks via agent-scope atomics.
// ---------------------------------------------------------------------------

typedef unsigned short u16;
typedef unsigned long long u64;
typedef __attribute__((ext_vector_type(8))) short short8;   // 8 x bf16 bits
typedef __attribute__((ext_vector_type(4))) short short4v;  // 4 x bf16 bits
typedef __attribute__((ext_vector_type(4))) float f32x4;

__device__ __forceinline__ u16 f2bf(float f) {
  union { float f; unsigned u; } v; v.f = f;
  unsigned r = v.u + 0x7fffu + ((v.u >> 16) & 1u);  // RNE
  return (u16)(r >> 16);
}

__device__ __forceinline__ float sigm(float x) { return 1.f / (1.f + __expf(-x)); }
__device__ __forceinline__ float tanh_fast(float x) {
  float e = __expf(-2.f * fabsf(x));
  float t = (1.f - e) / (1.f + e);
  return x < 0.f ? -t : t;
}

// --------------------------- elementwise f32 -> bf16 ------------------------
__global__ void conv_kernel(const float* __restrict__ in, u16* __restrict__ out, long n) {
  long i = ((long)blockIdx.x * 256 + threadIdx.x) * 4;
  if (i < n) {
    float4 v = *(const float4*)(in + i);
    union { short4v s4; u16 s[4]; } pk;
    pk.s[0] = f2bf(v.x); pk.s[1] = f2bf(v.y); pk.s[2] = f2bf(v.z); pk.s[3] = f2bf(v.w);
    *(short4v*)(out + i) = pk.s4;
  }
}

// --------------------- transpose + convert: f32[K][N] -> bf16[N][K] ---------
__global__ void tconv_kernel(const float* __restrict__ in, u16* __restrict__ out,
                             int K, int N, long sIn, long sOut) {
  __shared__ float tile[32][33];
  const int z = blockIdx.z;
  in += (long)z * sIn; out += (long)z * sOut;
  const int nt = blockIdx.x * 32, kt = blockIdx.y * 32;
  const int tx = threadIdx.x & 31, ty = (threadIdx.x >> 5) * 4;
#pragma unroll
  for (int r = 0; r < 4; ++r)
    tile[ty + r][tx] = in[(long)(kt + ty + r) * N + nt + tx];
  __syncthreads();
#pragma unroll
  for (int r = 0; r < 4; ++r)
    out[(long)(nt + ty + r) * K + kt + tx] = f2bf(tile[tx][ty + r]);
}

// --------------------------- bfold = din_b @ k0 + b0 ------------------------
__global__ void bfold_kernel(const float* __restrict__ din_b, const float* __restrict__ k0,
                             const float* __restrict__ b0, float* __restrict__ bf) {
  int n = blockIdx.x * 256 + threadIdx.x;  // 0..2047
  float acc = b0[n];
  for (int k = 0; k < 512; ++k) acc += din_b[k] * k0[(long)k * 2048 + n];
  bf[n] = acc;
}

// ------------------- softmax over rows of 512 (one wave per row) ------------
__global__ __launch_bounds__(256) void softmax_kernel(const float* __restrict__ in,
                                                      u16* __restrict__ out) {
  const int row = blockIdx.x * 4 + (threadIdx.x >> 6);
  const int lane = threadIdx.x & 63;
  const float* p = in + (long)row * 512 + lane * 8;
  float4 a = *(const float4*)p, b = *(const float4*)(p + 4);
  float v[8] = {a.x, a.y, a.z, a.w, b.x, b.y, b.z, b.w};
  float m = v[0];
#pragma unroll
  for (int i = 1; i < 8; ++i) m = fmaxf(m, v[i]);
  for (int o = 32; o > 0; o >>= 1) m = fmaxf(m, __shfl_xor(m, o));
  float s = 0.f;
#pragma unroll
  for (int i = 0; i < 8; ++i) { v[i] = __expf(v[i] - m); s += v[i]; }
  for (int o = 32; o > 0; o >>= 1) s += __shfl_xor(s, o);
  const float inv = 1.f / s;
  union { short8 v8; u16 s2[8]; } pk;
#pragma unroll
  for (int i = 0; i < 8; ++i) pk.s2[i] = f2bf(v[i] * inv);
  *(short8*)(out + (long)row * 512 + lane * 8) = pk.v8;
}

// ---------------------------------------------------------------------------
// Generic "BT" MFMA GEMM: C[m][n] = sum_k A[m][k] * B[n][k]  (both K-contig)
// ---------------------------------------------------------------------------
template <int STAGEA, int EPI, bool HASBIAS>
__global__ __launch_bounds__(256, 2) void gemm_bt_kernel(
    const u16* __restrict__ Ab, const float* __restrict__ Af,
    const u16* __restrict__ Bb,
    float* __restrict__ Cf, u16* __restrict__ Cb,
    const float* __restrict__ bias, const int* __restrict__ gather,
    const int* __restrict__ mask, int maskld,
    int M, int N, int K, long sA, long sB, long sC, long sMask) {
  constexpr int BM = 128, BK = 32, LDST = 40;
  __shared__ u16 As[BM * LDST];
  __shared__ u16 Bs[BM * LDST];
  const int z = blockIdx.z;
  const int m0 = blockIdx.y * BM, n0 = blockIdx.x * BM;
  const int t = threadIdx.x;
  const int trow = t >> 2, tkc = t & 3;
  const int wid = t >> 6, lane = t & 63;
  const int mq = (wid & 1) * 64, nq = (wid >> 1) * 64;
  const int fr = lane & 15;
  const int fko = (lane >> 4) * 8;

  const u16* Bbz = Bb + (long)z * sB;
  const u16* bptr0 = Bbz + (long)(n0 + trow) * K + tkc * 8;
  const u16* bptr1 = bptr0 + (long)64 * K;

  const u16* aptr0 = nullptr; const u16* aptr1 = nullptr;
  const float* gptr0 = nullptr; const float* gptr1 = nullptr;
  if (STAGEA == 0) {
    const u16* Abz = Ab + (long)z * sA;
    aptr0 = Abz + (long)(m0 + trow) * K + tkc * 8;
    aptr1 = aptr0 + (long)64 * K;
  } else {
    int g0 = gather[m0 + trow];
    int g1 = gather[m0 + 64 + trow];
    gptr0 = Af + (long)g0 * K + tkc * 8;
    gptr1 = Af + (long)g1 * K + tkc * 8;
  }

  const f32x4 z4 = {0.f, 0.f, 0.f, 0.f};
  f32x4 acc[4][4];
#pragma unroll
  for (int i = 0; i < 4; ++i)
#pragma unroll
    for (int j = 0; j < 4; ++j) acc[i][j] = z4;

  u16* asw0 = &As[trow * LDST + tkc * 8];
  u16* asw1 = &As[(64 + trow) * LDST + tkc * 8];
  u16* bsw0 = &Bs[trow * LDST + tkc * 8];
  u16* bsw1 = &Bs[(64 + trow) * LDST + tkc * 8];

  for (int k0 = 0; k0 < K; k0 += BK) {
    if (STAGEA == 0) {
      *(short8*)asw0 = *(const short8*)(aptr0 + k0);
      *(short8*)asw1 = *(const short8*)(aptr1 + k0);
    } else {
      float4 u0 = *(const float4*)(gptr0 + k0);
      float4 u1 = *(const float4*)(gptr0 + k0 + 4);
      union { short8 v; u16 s[8]; } pk;
      pk.s[0] = f2bf(u0.x); pk.s[1] = f2bf(u0.y); pk.s[2] = f2bf(u0.z); pk.s[3] = f2bf(u0.w);
      pk.s[4] = f2bf(u1.x); pk.s[5] = f2bf(u1.y); pk.s[6] = f2bf(u1.z); pk.s[7] = f2bf(u1.w);
      *(short8*)asw0 = pk.v;
      float4 w0 = *(const float4*)(gptr1 + k0);
      float4 w1 = *(const float4*)(gptr1 + k0 + 4);
      pk.s[0] = f2bf(w0.x); pk.s[1] = f2bf(w0.y); pk.s[2] = f2bf(w0.z); pk.s[3] = f2bf(w0.w);
      pk.s[4] = f2bf(w1.x); pk.s[5] = f2bf(w1.y); pk.s[6] = f2bf(w1.z); pk.s[7] = f2bf(w1.w);
      *(short8*)asw1 = pk.v;
    }
    *(short8*)bsw0 = *(const short8*)(bptr0 + k0);
    *(short8*)bsw1 = *(const short8*)(bptr1 + k0);
    __syncthreads();
    short8 afr[4], bfr[4];
#pragma unroll
    for (int i = 0; i < 4; ++i) afr[i] = *(const short8*)&As[(mq + i * 16 + fr) * LDST + fko];
#pragma unroll
    for (int j = 0; j < 4; ++j) bfr[j] = *(const short8*)&Bs[(nq + j * 16 + fr) * LDST + fko];
#pragma unroll
    for (int i = 0; i < 4; ++i)
#pragma unroll
      for (int j = 0; j < 4; ++j)
        acc[i][j] = __builtin_amdgcn_mfma_f32_16x16x32_bf16(afr[i], bfr[j], acc[i][j], 0, 0, 0);
    __syncthreads();
  }

  const int r4b = (lane >> 4) * 4;
#pragma unroll
  for (int j = 0; j < 4; ++j) {
    const int n = n0 + nq + j * 16 + fr;
    float bv = 0.f;
    if (HASBIAS) bv = bias[n];
#pragma unroll
    for (int i = 0; i < 4; ++i) {
      const int mb = m0 + mq + i * 16 + r4b;
      if (EPI == 0) {
#pragma unroll
        for (int r = 0; r < 4; ++r)
          Cb[(long)z * sC + (long)(mb + r) * N + n] = f2bf(acc[i][j][r] + bv);
      } else if (EPI == 1) {
#pragma unroll
        for (int r = 0; r < 4; ++r)
          Cf[(long)z * sC + (long)(mb + r) * N + n] = acc[i][j][r] + bv;
      } else if (EPI == 2) {
#pragma unroll
        for (int r = 0; r < 4; ++r) {
          float mv = (float)mask[(long)z * sMask + (long)n * maskld + (mb + r)];
          Cf[(long)z * sC + (long)(mb + r) * N + n] = acc[i][j][r] + mv * -1e9f;
        }
      } else {
        union { short4v v; u16 s[4]; } pk2;
#pragma unroll
        for (int r = 0; r < 4; ++r) pk2.s[r] = f2bf(acc[i][j][r]);
        *(short4v*)&Cb[(long)n * M + mb] = pk2.v;
      }
    }
  }
}

// ---------------------------------------------------------------------------
// Persistent merged 2-layer LSTM. 64 blocks x 256 threads. Phase t: layer0
// step t + layer1 step t-1 for this block's 16-batch x 16-unit tile (wave =
// gate). Weights r0/k1/r1 register-resident (48 short8). h0 A-frags reused
// for both r0- and k1-MFMAs. Barrier: 64 per-block epoch slots, every thread
// polls one slot -> no syncthreads around the device barrier.
// ---------------------------------------------------------------------------
__global__ __launch_bounds__(256, 1) void lstm_kernel(
    const u16* __restrict__ wt_r0, const u16* __restrict__ wt_k1,
    const u16* __restrict__ wt_r1, const float* __restrict__ xk0,
    const float* __restrict__ b1, u16* __restrict__ h0b, u16* __restrict__ h1b,
    float* __restrict__ out, int* __restrict__ slots) {
  constexpr int HST = 520;  // u16 row stride (+8 pad)
  __shared__ u16 hst[2][16 * HST];      // 33 KB
  __shared__ float zs[2][3][4][64];     // 6 KB  [layer][srcwave-1][r][lane]
  __shared__ u16 htile[2][16][16];      // 1 KB
  const int bid = blockIdx.x;
  const int mtile = bid & 1;    // batch half: rows mtile*16..+15
  const int grp = bid >> 1;     // 16-unit group, 0..31
  const int tid = threadIdx.x;
  const int wid = tid >> 6, lane = tid & 63;
  const int fr = lane & 15;
  const int fko = (lane >> 4) * 8;
  const int r4b = (lane >> 4) * 4;
  const int u = grp * 16 + fr;          // unit index
  const int col = wid * 512 + u;        // gate column (wave = gate i,f,g,o)

  // ---- all three weight sets into registers, unconditionally ----
  short8 wR0[16], wK1[16], wR1[16];
  {
    const u16* p0 = wt_r0 + (long)col * 512 + fko;
    const u16* p1 = wt_k1 + (long)col * 512 + fko;
    const u16* p2 = wt_r1 + (long)col * 512 + fko;
#pragma unroll
    for (int ks = 0; ks < 16; ++ks) {
      wR0[ks] = *(const short8*)(p0 + ks * 32);
      wK1[ks] = *(const short8*)(p1 + ks * 32);
      wR1[ks] = *(const short8*)(p2 + ks * 32);
    }
  }
  const float blw = b1[col];   // layer-1 bias for this gate/unit
  float cst0[4] = {0.f, 0.f, 0.f, 0.f};
  float cst1[4] = {0.f, 0.f, 0.f, 0.f};

  // stage-loader mapping: thread -> (row sr, u64 chunk i + 64-col step j)
  const int sr = tid >> 4;           // 0..15
  const int si = (tid & 15) * 4;     // u16 col base within 64-col step
  const long gbase = (long)(mtile * 16 + sr) * 512 + si;
  const int myslot = (tid & 63) * 32;

#pragma unroll 1
  for (int t = -1; t <= 256; ++t) {
    if (t < 0) {
      // zero-init h0(-1) -> h0b[buf1], h1(-1) -> h1b[buf0] (this block's tile)
      if (wid == 0) {
        const int rr = lane >> 2, cc = (lane & 3) * 4;
        const long o = (long)(mtile * 16 + rr) * 512 + grp * 16 + cc;
        __hip_atomic_store((u64*)&h0b[32 * 512 + o], (u64)0,
                           __ATOMIC_RELAXED, __HIP_MEMORY_SCOPE_AGENT);
        __hip_atomic_store((u64*)&h1b[o], (u64)0,
                           __ATOMIC_RELAXED, __HIP_MEMORY_SCOPE_AGENT);
        __builtin_amdgcn_s_waitcnt(0);
        if (tid == 0)
          __hip_atomic_store(&slots[bid * 32], 1, __ATOMIC_RELAXED, __HIP_MEMORY_SCOPE_AGENT);
      }
    } else {
      // ---- hoisted xk0 loads (independent of h; hides under stage+MFMA) ----
      float xadd[4];
      if (t < 256) {
#pragma unroll
        for (int r = 0; r < 4; ++r)
          xadd[r] = xk0[((long)(mtile * 16 + r4b + r) * 256 + t) * 2048 + col];
      }
      // ---- stage h0(t-1) (and h1(t-2) when needed) into LDS ----
      const int rd = (t + 1) & 1;
      const u16* src0 = h0b + rd * (32 * 512);
#pragma unroll
      for (int j = 0; j < 8; ++j) {
        u64 v = __hip_atomic_load((const u64*)(src0 + gbase + j * 64),
                                  __ATOMIC_RELAXED, __HIP_MEMORY_SCOPE_AGENT);
        *(u64*)&hst[0][sr * HST + si + j * 64] = v;
      }
      if (t >= 1) {
        const u16* src1 = h1b + rd * (32 * 512);
#pragma unroll
        for (int j = 0; j < 8; ++j) {
          u64 v = __hip_atomic_load((const u64*)(src1 + gbase + j * 64),
                                    __ATOMIC_RELAXED, __HIP_MEMORY_SCOPE_AGENT);
          *(u64*)&hst[1][sr * HST + si + j * 64] = v;
        }
      }
      __syncthreads();  // D: stage visible
      // ---- MFMAs: acc0 = h0@r0 (layer0), acc1 = h0@k1 + h1@r1 (layer1) ----
      f32x4 acc0 = {0.f, 0.f, 0.f, 0.f};
      f32x4 acc1 = {0.f, 0.f, 0.f, 0.f};
#pragma unroll
      for (int ks = 0; ks < 16; ++ks) {
        short8 a0 = *(const short8*)&hst[0][fr * HST + fko + ks * 32];
        acc0 = __builtin_amdgcn_mfma_f32_16x16x32_bf16(a0, wR0[ks], acc0, 0, 0, 0);
        acc1 = __builtin_amdgcn_mfma_f32_16x16x32_bf16(a0, wK1[ks], acc1, 0, 0, 0);
      }
      if (t >= 1) {
#pragma unroll
        for (int ks = 0; ks < 16; ++ks) {
          short8 a1 = *(const short8*)&hst[1][fr * HST + fko + ks * 32];
          acc1 = __builtin_amdgcn_mfma_f32_16x16x32_bf16(a1, wR1[ks], acc1, 0, 0, 0);
        }
      }
      if (t < 256) {
#pragma unroll
        for (int r = 0; r < 4; ++r) acc0[r] += xadd[r];
      }
#pragma unroll
      for (int r = 0; r < 4; ++r) acc1[r] += blw;
      if (wid > 0) {
#pragma unroll
        for (int r = 0; r < 4; ++r) {
          zs[0][wid - 1][r][lane] = acc0[r];
          zs[1][wid - 1][r][lane] = acc1[r];
        }
      }
      __syncthreads();  // A: zs visible to wave0
      if (wid == 0) {
        const int rr = lane >> 2, cc = (lane & 3) * 4;
        const long o = (long)(mtile * 16 + rr) * 512 + grp * 16 + cc;
        const int wr = t & 1;
        if (t < 256) {  // layer 0 pointwise + h0(t) store
#pragma unroll
          for (int r = 0; r < 4; ++r) {
            float zi = acc0[r], zf = zs[0][0][r][lane];
            float zg = zs[0][1][r][lane], zo = zs[0][2][r][lane];
            float cn = sigm(zf) * cst0[r] + sigm(zi) * tanh_fast(zg);
            cst0[r] = cn;
            htile[0][r4b + r][fr] = f2bf(sigm(zo) * tanh_fast(cn));
          }
          u64 v0 = *(const u64*)&htile[0][rr][cc];
          __hip_atomic_store((u64*)&h0b[wr * (32 * 512) + o], v0,
                             __ATOMIC_RELAXED, __HIP_MEMORY_SCOPE_AGENT);
        }
        if (t >= 1) {   // layer 1 pointwise (step t-1) + h1(t-1) store + out
          const int tt = t - 1;
#pragma unroll
          for (int r = 0; r < 4; ++r) {
            float zi = acc1[r], zf = zs[1][0][r][lane];
            float zg = zs[1][1][r][lane], zo = zs[1][2][r][lane];
            float cn = sigm(zf) * cst1[r] + sigm(zi) * tanh_fast(zg);
            cst1[r] = cn;
            float h = sigm(zo) * tanh_fast(cn);
            htile[1][r4b + r][fr] = f2bf(h);
            out[((long)(mtile * 16 + r4b + r) * 256 + tt) * 512 + u] = h;
          }
          u64 v1 = *(const u64*)&htile[1][rr][cc];
          __hip_atomic_store((u64*)&h1b[wr * (32 * 512) + o], v1,
                             __ATOMIC_RELAXED, __HIP_MEMORY_SCOPE_AGENT);
        }
        __builtin_amdgcn_s_waitcnt(0);  // h stores at coherence point
        if (tid == 0 && t < 256)
          __hip_atomic_store(&slots[bid * 32], t + 2, __ATOMIC_RELAXED,
                             __HIP_MEMORY_SCOPE_AGENT);
      }
    }
    // ---- distributed barrier: every thread polls its own slot ----
    if (t < 256) {
      const int ep = t + 2;  // 1..257
      while (__hip_atomic_load(&slots[myslot], __ATOMIC_RELAXED,
                               __HIP_MEMORY_SCOPE_AGENT) < ep)
        __builtin_amdgcn_s_sleep(1);
    }
  }
}

// ---------------------------------------------------------------------------
extern "C" void kernel_launch(void* const* d_in, const int* in_sizes, int n_in,
                              void* d_out, int out_size, void* d_ws, size_t ws_size,
                              hipStream_t stream) {
  (void)in_sizes; (void)n_in; (void)out_size; (void)ws_size;
  const float* enc   = (const float*)d_in[0];
  const int*   lw    = (const int*)d_in[1];
  const int*   mask  = (const int*)d_in[2];
  const float* P_w   = (const float*)d_in[3];
  const float* P_b   = (const float*)d_in[4];
  const float* emb   = (const float*)d_in[5];
  const float* din_w = (const float*)d_in[6];
  const float* din_b = (const float*)d_in[7];
  const float* k0    = (const float*)d_in[8];
  const float* r0    = (const float*)d_in[9];
  const float* b0    = (const float*)d_in[10];
  const float* k1    = (const float*)d_in[11];
  const float* r1    = (const float*)d_in[12];
  const float* b1    = (const float*)d_in[13];
  float* out = (float*)d_out;

  char* base = (char*)d_ws;
  size_t off = 0;
  auto alloc = [&](size_t b) -> void* {
    void* p = base + off;
    off = (off + b + 255) & ~(size_t)255;
    return p;
  };
  float* xk0  = (float*)alloc(8192UL * 2048 * 4);   // 67 MB
  u16* encb   = (u16*)alloc(32UL * 512 * 512 * 2);
  u16* encT   = (u16*)alloc(32UL * 512 * 512 * 2);
  float* aTf  = (float*)alloc(32UL * 256 * 512 * 4);
  u16* aTb    = (u16*)alloc(32UL * 256 * 512 * 2);
  u16* pd     = (u16*)alloc(8192UL * 512 * 2);
  u16* wt_r0  = (u16*)alloc(2048UL * 512 * 2);
  u16* wt_k1  = (u16*)alloc(2048UL * 512 * 2);
  u16* wt_r1  = (u16*)alloc(2048UL * 512 * 2);
  u16* k0T    = (u16*)alloc(2048UL * 512 * 2);
  u16* PwT    = (u16*)alloc(512UL * 512 * 2);
  u16* dinwb  = (u16*)alloc(512UL * 512 * 2);
  u16* WfT    = (u16*)alloc(2048UL * 512 * 2);
  float* bfld = (float*)alloc(2048 * 4);
  u16* h0b    = (u16*)alloc(2UL * 32 * 512 * 2);
  u16* h1b    = (u16*)alloc(2UL * 32 * 512 * 2);
  int* slots  = (int*)alloc(64 * 32 * 4);           // 8 KB epoch slots

  conv_kernel<<<8192, 256, 0, stream>>>(enc, encb, 32L * 512 * 512);
  tconv_kernel<<<dim3(16, 16, 32), 256, 0, stream>>>(enc, encT, 512, 512, 262144, 262144);
  tconv_kernel<<<dim3(64, 16, 1), 256, 0, stream>>>(r0, wt_r0, 512, 2048, 0, 0);
  tconv_kernel<<<dim3(64, 16, 1), 256, 0, stream>>>(k1, wt_k1, 512, 2048, 0, 0);
  tconv_kernel<<<dim3(64, 16, 1), 256, 0, stream>>>(r1, wt_r1, 512, 2048, 0, 0);
  tconv_kernel<<<dim3(64, 16, 1), 256, 0, stream>>>(k0, k0T, 512, 2048, 0, 0);
  tconv_kernel<<<dim3(16, 16, 1), 256, 0, stream>>>(P_w, PwT, 512, 512, 0, 0);
  conv_kernel<<<256, 256, 0, stream>>>(din_w, dinwb, 512L * 512);

  // K1: py = emb[lw] @ P_w + P_b -> pd (bf16)
  gemm_bt_kernel<1, 0, true><<<dim3(4, 64, 1), 256, 0, stream>>>(
      nullptr, emb, PwT, nullptr, pd, P_b, lw, nullptr, 0,
      8192, 512, 512, 0, 0, 0, 0);
  // K5: WfT = (din_w @ k0)^T
  gemm_bt_kernel<0, 3, false><<<dim3(16, 4, 1), 256, 0, stream>>>(
      dinwb, nullptr, k0T, nullptr, WfT, nullptr, nullptr, nullptr, 0,
      512, 2048, 512, 0, 0, 0, 0);
  bfold_kernel<<<8, 256, 0, stream>>>(din_b, k0, b0, bfld);
  // K2: scores + mask
  gemm_bt_kernel<0, 2, false><<<dim3(4, 2, 32), 256, 0, stream>>>(
      pd, nullptr, encb, aTf, nullptr, nullptr, nullptr, mask, 256,
      256, 512, 512, 131072, 262144, 131072, 131072);
  softmax_kernel<<<2048, 256, 0, stream>>>(aTf, aTb);
  // K4: dec = softmax @ enc
  gemm_bt_kernel<0, 0, false><<<dim3(4, 2, 32), 256, 0, stream>>>(
      aTb, nullptr, encT, nullptr, pd, nullptr, nullptr, nullptr, 0,
      256, 512, 512, 131072, 262144, 131072, 0);
  // K6: xk0 = dec @ (din_w@k0) + folded bias
  gemm_bt_kernel<0, 1, true><<<dim3(16, 64, 1), 256, 0, stream>>>(
      pd, nullptr, WfT, xk0, nullptr, bfld, nullptr, nullptr, 0,
      8192, 2048, 512, 0, 0, 0, 0);

  hipMemsetAsync(slots, 0, 64 * 32 * 4, stream);
  lstm_kernel<<<64, 256, 0, stream>>>(wt_r0, wt_k1, wt_r1, xk0, b1, h0b, h1b, out, slots);
}

// Round 5
// 2424.664 us; speedup vs baseline: 1.0648x; 1.0648x over previous
//
#include <hip/hip_runtime.h>
#include <cstdint>

// ---------------------------------------------------------------------------
// LSTMdecoder: attention prelude (bf16 MFMA GEMMs) + 2-layer LSTM over 256
// steps as a persistent kernel. 192 blocks: bid<64 = layer0 (16 units/block,
// r0 in LDS), bid>=64 = layer1 (8 units/block, k1+r1 in LDS). h staged via
// LDS from agent-scope u64 atomics; complete 192-slot distributed barrier,
// slot posted by tid0 after its own store drain. out-stores deferred a phase.
// ---------------------------------------------------------------------------

typedef unsigned short u16;
typedef unsigned long long u64;
typedef __attribute__((ext_vector_type(8))) short short8;   // 8 x bf16 bits
typedef __attribute__((ext_vector_type(4))) short short4v;  // 4 x bf16 bits
typedef __attribute__((ext_vector_type(4))) float f32x4;

__device__ __forceinline__ u16 f2bf(float f) {
  union { float f; unsigned u; } v; v.f = f;
  unsigned r = v.u + 0x7fffu + ((v.u >> 16) & 1u);  // RNE
  return (u16)(r >> 16);
}

__device__ __forceinline__ float sigm(float x) { return 1.f / (1.f + __expf(-x)); }
__device__ __forceinline__ float tanh_fast(float x) {
  float e = __expf(-2.f * fabsf(x));
  float t = (1.f - e) / (1.f + e);
  return x < 0.f ? -t : t;
}

// --------------------------- elementwise f32 -> bf16 ------------------------
__global__ void conv_kernel(const float* __restrict__ in, u16* __restrict__ out, long n) {
  long i = ((long)blockIdx.x * 256 + threadIdx.x) * 4;
  if (i < n) {
    float4 v = *(const float4*)(in + i);
    union { short4v s4; u16 s[4]; } pk;
    pk.s[0] = f2bf(v.x); pk.s[1] = f2bf(v.y); pk.s[2] = f2bf(v.z); pk.s[3] = f2bf(v.w);
    *(short4v*)(out + i) = pk.s4;
  }
}

// --------------------- transpose + convert: f32[K][N] -> bf16[N][K] ---------
__global__ void tconv_kernel(const float* __restrict__ in, u16* __restrict__ out,
                             int K, int N, long sIn, long sOut) {
  __shared__ float tile[32][33];
  const int z = blockIdx.z;
  in += (long)z * sIn; out += (long)z * sOut;
  const int nt = blockIdx.x * 32, kt = blockIdx.y * 32;
  const int tx = threadIdx.x & 31, ty = (threadIdx.x >> 5) * 4;
#pragma unroll
  for (int r = 0; r < 4; ++r)
    tile[ty + r][tx] = in[(long)(kt + ty + r) * N + nt + tx];
  __syncthreads();
#pragma unroll
  for (int r = 0; r < 4; ++r)
    out[(long)(nt + ty + r) * K + kt + tx] = f2bf(tile[tx][ty + r]);
}

// --------------------------- bfold = din_b @ k0 + b0 ------------------------
__global__ void bfold_kernel(const float* __restrict__ din_b, const float* __restrict__ k0,
                             const float* __restrict__ b0, float* __restrict__ bf) {
  int n = blockIdx.x * 256 + threadIdx.x;  // 0..2047
  float acc = b0[n];
  for (int k = 0; k < 512; ++k) acc += din_b[k] * k0[(long)k * 2048 + n];
  bf[n] = acc;
}

// ------------------- softmax over rows of 512 (one wave per row) ------------
__global__ __launch_bounds__(256) void softmax_kernel(const float* __restrict__ in,
                                                      u16* __restrict__ out) {
  const int row = blockIdx.x * 4 + (threadIdx.x >> 6);
  const int lane = threadIdx.x & 63;
  const float* p = in + (long)row * 512 + lane * 8;
  float4 a = *(const float4*)p, b = *(const float4*)(p + 4);
  float v[8] = {a.x, a.y, a.z, a.w, b.x, b.y, b.z, b.w};
  float m = v[0];
#pragma unroll
  for (int i = 1; i < 8; ++i) m = fmaxf(m, v[i]);
  for (int o = 32; o > 0; o >>= 1) m = fmaxf(m, __shfl_xor(m, o));
  float s = 0.f;
#pragma unroll
  for (int i = 0; i < 8; ++i) { v[i] = __expf(v[i] - m); s += v[i]; }
  for (int o = 32; o > 0; o >>= 1) s += __shfl_xor(s, o);
  const float inv = 1.f / s;
  union { short8 v8; u16 s2[8]; } pk;
#pragma unroll
  for (int i = 0; i < 8; ++i) pk.s2[i] = f2bf(v[i] * inv);
  *(short8*)(out + (long)row * 512 + lane * 8) = pk.v8;
}

// ---------------------------------------------------------------------------
// Generic "BT" MFMA GEMM: C[m][n] = sum_k A[m][k] * B[n][k]  (both K-contig)
// ---------------------------------------------------------------------------
template <int STAGEA, int EPI, bool HASBIAS>
__global__ __launch_bounds__(256, 2) void gemm_bt_kernel(
    const u16* __restrict__ Ab, const float* __restrict__ Af,
    const u16* __restrict__ Bb,
    float* __restrict__ Cf, u16* __restrict__ Cb,
    const float* __restrict__ bias, const int* __restrict__ gather,
    const int* __restrict__ mask, int maskld,
    int M, int N, int K, long sA, long sB, long sC, long sMask) {
  constexpr int BM = 128, BK = 32, LDST = 40;
  __shared__ u16 As[BM * LDST];
  __shared__ u16 Bs[BM * LDST];
  const int z = blockIdx.z;
  const int m0 = blockIdx.y * BM, n0 = blockIdx.x * BM;
  const int t = threadIdx.x;
  const int trow = t >> 2, tkc = t & 3;
  const int wid = t >> 6, lane = t & 63;
  const int mq = (wid & 1) * 64, nq = (wid >> 1) * 64;
  const int fr = lane & 15;
  const int fko = (lane >> 4) * 8;

  const u16* Bbz = Bb + (long)z * sB;
  const u16* bptr0 = Bbz + (long)(n0 + trow) * K + tkc * 8;
  const u16* bptr1 = bptr0 + (long)64 * K;

  const u16* aptr0 = nullptr; const u16* aptr1 = nullptr;
  const float* gptr0 = nullptr; const float* gptr1 = nullptr;
  if (STAGEA == 0) {
    const u16* Abz = Ab + (long)z * sA;
    aptr0 = Abz + (long)(m0 + trow) * K + tkc * 8;
    aptr1 = aptr0 + (long)64 * K;
  } else {
    int g0 = gather[m0 + trow];
    int g1 = gather[m0 + 64 + trow];
    gptr0 = Af + (long)g0 * K + tkc * 8;
    gptr1 = Af + (long)g1 * K + tkc * 8;
  }

  const f32x4 z4 = {0.f, 0.f, 0.f, 0.f};
  f32x4 acc[4][4];
#pragma unroll
  for (int i = 0; i < 4; ++i)
#pragma unroll
    for (int j = 0; j < 4; ++j) acc[i][j] = z4;

  u16* asw0 = &As[trow * LDST + tkc * 8];
  u16* asw1 = &As[(64 + trow) * LDST + tkc * 8];
  u16* bsw0 = &Bs[trow * LDST + tkc * 8];
  u16* bsw1 = &Bs[(64 + trow) * LDST + tkc * 8];

  for (int k0 = 0; k0 < K; k0 += BK) {
    if (STAGEA == 0) {
      *(short8*)asw0 = *(const short8*)(aptr0 + k0);
      *(short8*)asw1 = *(const short8*)(aptr1 + k0);
    } else {
      float4 u0 = *(const float4*)(gptr0 + k0);
      float4 u1 = *(const float4*)(gptr0 + k0 + 4);
      union { short8 v; u16 s[8]; } pk;
      pk.s[0] = f2bf(u0.x); pk.s[1] = f2bf(u0.y); pk.s[2] = f2bf(u0.z); pk.s[3] = f2bf(u0.w);
      pk.s[4] = f2bf(u1.x); pk.s[5] = f2bf(u1.y); pk.s[6] = f2bf(u1.z); pk.s[7] = f2bf(u1.w);
      *(short8*)asw0 = pk.v;
      float4 w0 = *(const float4*)(gptr1 + k0);
      float4 w1 = *(const float4*)(gptr1 + k0 + 4);
      pk.s[0] = f2bf(w0.x); pk.s[1] = f2bf(w0.y); pk.s[2] = f2bf(w0.z); pk.s[3] = f2bf(w0.w);
      pk.s[4] = f2bf(w1.x); pk.s[5] = f2bf(w1.y); pk.s[6] = f2bf(w1.z); pk.s[7] = f2bf(w1.w);
      *(short8*)asw1 = pk.v;
    }
    *(short8*)bsw0 = *(const short8*)(bptr0 + k0);
    *(short8*)bsw1 = *(const short8*)(bptr1 + k0);
    __syncthreads();
    short8 afr[4], bfr[4];
#pragma unroll
    for (int i = 0; i < 4; ++i) afr[i] = *(const short8*)&As[(mq + i * 16 + fr) * LDST + fko];
#pragma unroll
    for (int j = 0; j < 4; ++j) bfr[j] = *(const short8*)&Bs[(nq + j * 16 + fr) * LDST + fko];
#pragma unroll
    for (int i = 0; i < 4; ++i)
#pragma unroll
      for (int j = 0; j < 4; ++j)
        acc[i][j] = __builtin_amdgcn_mfma_f32_16x16x32_bf16(afr[i], bfr[j], acc[i][j], 0, 0, 0);
    __syncthreads();
  }

  const int r4b = (lane >> 4) * 4;
#pragma unroll
  for (int j = 0; j < 4; ++j) {
    const int n = n0 + nq + j * 16 + fr;
    float bv = 0.f;
    if (HASBIAS) bv = bias[n];
#pragma unroll
    for (int i = 0; i < 4; ++i) {
      const int mb = m0 + mq + i * 16 + r4b;
      if (EPI == 0) {
#pragma unroll
        for (int r = 0; r < 4; ++r)
          Cb[(long)z * sC + (long)(mb + r) * N + n] = f2bf(acc[i][j][r] + bv);
      } else if (EPI == 1) {
#pragma unroll
        for (int r = 0; r < 4; ++r)
          Cf[(long)z * sC + (long)(mb + r) * N + n] = acc[i][j][r] + bv;
      } else if (EPI == 2) {
#pragma unroll
        for (int r = 0; r < 4; ++r) {
          float mv = (float)mask[(long)z * sMask + (long)n * maskld + (mb + r)];
          Cf[(long)z * sC + (long)(mb + r) * N + n] = acc[i][j][r] + mv * -1e9f;
        }
      } else {
        union { short4v v; u16 s[4]; } pk2;
#pragma unroll
        for (int r = 0; r < 4; ++r) pk2.s[r] = f2bf(acc[i][j][r]);
        *(short4v*)&Cb[(long)n * M + mb] = pk2.v;
      }
    }
  }
}

// ---------------------------------------------------------------------------
// Persistent split 2-layer LSTM. 192 blocks x 256 threads.
//   bid 0..63   : layer0, tile 16 batch x 16 units (r0 in LDS, 64 rows)
//   bid 64..191 : layer1, tile 16 batch x  8 units (k1+r1 in LDS, 32+32 rows)
// Phase t: L0 computes step t, L1 computes step t-1. h staged via LDS from
// agent-scope u64 loads (R2-proven). Complete 192-slot barrier; slot posted
// by tid0 after its own h-store drain. out-stores deferred one phase.
// ---------------------------------------------------------------------------
__global__ __launch_bounds__(256, 1) void lstm_kernel(
    const u16* __restrict__ wt_r0, const u16* __restrict__ wt_k1,
    const u16* __restrict__ wt_r1, const float* __restrict__ xk0,
    const float* __restrict__ b1, u16* __restrict__ h0b, u16* __restrict__ h1b,
    float* __restrict__ out, int* __restrict__ slots) {
  constexpr int WST = 536, HST = 536;     // u16 strides, 16B-aligned rows
  __shared__ u16 WW[64 * WST];            // 68.6 KB weights
  __shared__ u16 hst[2][16 * HST];        // 34.3 KB h stage (h0 / h1)
  __shared__ float zs[3][4][64];          // 3 KB
  __shared__ u16 htile[16][16];           // 0.5 KB
  const int bid = blockIdx.x;
  const bool isL1 = bid >= 64;
  const int b2 = isL1 ? bid - 64 : bid;
  const int mtile = b2 & 1;               // batch half
  const int grp = b2 >> 1;                // L0: 0..31 ; L1: 0..63
  const int ubase = isL1 ? grp * 8 : grp * 16;
  const int tid = threadIdx.x;
  const int wid = tid >> 6, lane = tid & 63;
  const int fr = lane & 15, ko = lane >> 4;
  const int fko = ko * 8, r4b = ko * 4;
  const int usub = isL1 ? (fr & 7) : fr;
  const int u = ubase + usub;
  const int col = wid * 512 + u;          // gate column (wave = gate i,f,g,o)

  // ---- one-time: weight tiles -> LDS (plain row-major, padded stride) ----
  for (int c = tid; c < 1024; c += 256) {
    const int row = c >> 4, ks = c & 15;
    const u16* src; int scol;
    if (!isL1) {
      scol = (row >> 4) * 512 + ubase + (row & 15);   // gate, unit
      src = wt_r0;
    } else {
      const int rr = row & 31;
      scol = (rr >> 3) * 512 + ubase + (rr & 7);
      src = (row < 32) ? wt_k1 : wt_r1;
    }
    const u16* s = src + (long)scol * 512 + ks * 32;
    u16* d = &WW[row * WST + ks * 32];
#pragma unroll
    for (int k2 = 0; k2 < 4; ++k2)
      *(short8*)(d + k2 * 8) = *(const short8*)(s + k2 * 8);
  }
  const float blw = isL1 ? b1[col] : 0.f;
  float cst[4] = {0.f, 0.f, 0.f, 0.f};
  const int sr = tid >> 4;                // stage row (batch within half)
  const int si = (tid & 15) * 4;          // stage col base (conflict-free map)
  const long gbase = (long)(mtile * 16 + sr) * 512 + si;
  const u16* wrowA = &WW[(isL1 ? (wid * 8 + usub) : (wid * 16 + fr)) * WST];
  const u16* wrowB = &WW[(32 + wid * 8 + usub) * WST];  // L1: r1 rows
  float xnext[4] = {0.f, 0.f, 0.f, 0.f};
  float ho[4] = {0.f, 0.f, 0.f, 0.f};
  int hot = -1;                           // deferred out timestep
  __syncthreads();                        // weights staged

#pragma unroll 1
  for (int t = -1; t <= 256; ++t) {
    if (t < 0) {
      // zero-init: L0 -> h0b[buf1] tile ; L1 -> h1b[buf0] tile
      if (wid == 0) {
        if (!isL1) {
          const long o = (long)(mtile * 16 + (lane >> 2)) * 512 + ubase + (lane & 3) * 4;
          __hip_atomic_store((u64*)&h0b[32 * 512 + o], (u64)0,
                             __ATOMIC_RELAXED, __HIP_MEMORY_SCOPE_AGENT);
        } else if (lane < 32) {
          const long o = (long)(mtile * 16 + (lane >> 1)) * 512 + ubase + (lane & 1) * 4;
          __hip_atomic_store((u64*)&h1b[o], (u64)0,
                             __ATOMIC_RELAXED, __HIP_MEMORY_SCOPE_AGENT);
        }
        __builtin_amdgcn_s_waitcnt(0);
        if (tid == 0)
          __hip_atomic_store(&slots[bid * 32], 1, __ATOMIC_RELAXED,
                             __HIP_MEMORY_SCOPE_AGENT);
      }
    } else {
      const bool act = isL1 ? (t >= 1) : (t < 256);
      // deferred out-stores from previous phase (latency rides this phase)
      if (isL1 && wid == 0 && hot >= 0 && fr < 8) {
#pragma unroll
        for (int r = 0; r < 4; ++r)
          out[((long)(mtile * 16 + r4b + r) * 256 + hot) * 512 + u] = ho[r];
      }
      if (wid == 0) hot = -1;
      // ---- stage h into LDS (agent-scope u64 loads, conflict-free map) ----
      if (act) {
        const int rd = (t + 1) & 1;
        const u16* s0 = h0b + rd * (32 * 512);
#pragma unroll
        for (int j = 0; j < 8; ++j) {
          u64 v = __hip_atomic_load((const u64*)(s0 + gbase + j * 64),
                                    __ATOMIC_RELAXED, __HIP_MEMORY_SCOPE_AGENT);
          *(u64*)&hst[0][sr * HST + si + j * 64] = v;
        }
        if (isL1) {
          const u16* s1 = h1b + rd * (32 * 512);
#pragma unroll
          for (int j = 0; j < 8; ++j) {
            u64 v = __hip_atomic_load((const u64*)(s1 + gbase + j * 64),
                                      __ATOMIC_RELAXED, __HIP_MEMORY_SCOPE_AGENT);
            *(u64*)&hst[1][sr * HST + si + j * 64] = v;
          }
        }
      }
      __syncthreads();  // D: stage visible
      f32x4 z = {0.f, 0.f, 0.f, 0.f};
      if (act) {
        f32x4 acc0 = {0.f, 0.f, 0.f, 0.f};
#pragma unroll
        for (int ks = 0; ks < 16; ++ks) {
          short8 a = *(const short8*)&hst[0][fr * HST + fko + ks * 32];
          short8 b = *(const short8*)(wrowA + ks * 32 + fko);
          acc0 = __builtin_amdgcn_mfma_f32_16x16x32_bf16(a, b, acc0, 0, 0, 0);
        }
        if (!isL1) {
#pragma unroll
          for (int r = 0; r < 4; ++r) z[r] = acc0[r] + xnext[r];
        } else {
          f32x4 acc1 = {0.f, 0.f, 0.f, 0.f};
#pragma unroll
          for (int ks = 0; ks < 16; ++ks) {
            short8 a = *(const short8*)&hst[1][fr * HST + fko + ks * 32];
            short8 b = *(const short8*)(wrowB + ks * 32 + fko);
            acc1 = __builtin_amdgcn_mfma_f32_16x16x32_bf16(a, b, acc1, 0, 0, 0);
          }
#pragma unroll
          for (int r = 0; r < 4; ++r) z[r] = acc0[r] + acc1[r] + blw;
        }
        if (wid > 0) {
#pragma unroll
          for (int r = 0; r < 4; ++r) zs[wid - 1][r][lane] = z[r];
        }
      }
      __syncthreads();  // A: zs visible to wave0
      if (act && wid == 0) {
        const int tt = isL1 ? t - 1 : t;
        float hv[4];
#pragma unroll
        for (int r = 0; r < 4; ++r) {
          float zi = z[r], zf = zs[0][r][lane];
          float zg = zs[1][r][lane], zo = zs[2][r][lane];
          float cn = sigm(zf) * cst[r] + sigm(zi) * tanh_fast(zg);
          cst[r] = cn;
          hv[r] = sigm(zo) * tanh_fast(cn);
          if (!isL1 || fr < 8) htile[r4b + r][fr] = f2bf(hv[r]);
        }
        if (!isL1) {
          const int rr = lane >> 2, cc = (lane & 3) * 4;
          const long o = (long)(mtile * 16 + rr) * 512 + ubase + cc;
          u64 v = *(const u64*)&htile[rr][cc];
          __hip_atomic_store((u64*)&h0b[(t & 1) * (32 * 512) + o], v,
                             __ATOMIC_RELAXED, __HIP_MEMORY_SCOPE_AGENT);
        } else {
          if (lane < 32) {
            const int rr = lane >> 1, cc = (lane & 1) * 4;
            const long o = (long)(mtile * 16 + rr) * 512 + ubase + cc;
            u64 v = *(const u64*)&htile[rr][cc];
            __hip_atomic_store((u64*)&h1b[(t & 1) * (32 * 512) + o], v,
                               __ATOMIC_RELAXED, __HIP_MEMORY_SCOPE_AGENT);
          }
          if (fr < 8) {
#pragma unroll
            for (int r = 0; r < 4; ++r) ho[r] = hv[r];
          }
          hot = tt;  // defer out-store to next phase
        }
        __builtin_amdgcn_s_waitcnt(0);  // h globally visible before slot post
        if (tid == 0 && t < 256)
          __hip_atomic_store(&slots[bid * 32], t + 2, __ATOMIC_RELAXED,
                             __HIP_MEMORY_SCOPE_AGENT);
      }
      if (!act && tid == 0 && t < 256)
        __hip_atomic_store(&slots[bid * 32], t + 2, __ATOMIC_RELAXED,
                           __HIP_MEMORY_SCOPE_AGENT);
    }
    // ---- common: xk0 prefetch + complete distributed barrier ----
    if (t < 256) {
      if (!isL1 && t + 1 < 256) {
#pragma unroll
        for (int r = 0; r < 4; ++r)
          xnext[r] = xk0[((long)(mtile * 16 + r4b + r) * 256 + (t + 1)) * 2048 + col];
      }
      const int ep = t + 2;
      if (tid < 192) {
        while (__hip_atomic_load(&slots[tid * 32], __ATOMIC_RELAXED,
                                 __HIP_MEMORY_SCOPE_AGENT) < ep)
          __builtin_amdgcn_s_sleep(1);
      }
      __syncthreads();  // C
    }
  }
  // flush last deferred out (tt = 255)
  if (isL1 && wid == 0 && hot >= 0 && fr < 8) {
#pragma unroll
    for (int r = 0; r < 4; ++r)
      out[((long)(mtile * 16 + r4b + r) * 256 + hot) * 512 + u] = ho[r];
  }
}

// ---------------------------------------------------------------------------
extern "C" void kernel_launch(void* const* d_in, const int* in_sizes, int n_in,
                              void* d_out, int out_size, void* d_ws, size_t ws_size,
                              hipStream_t stream) {
  (void)in_sizes; (void)n_in; (void)out_size; (void)ws_size;
  const float* enc   = (const float*)d_in[0];
  const int*   lw    = (const int*)d_in[1];
  const int*   mask  = (const int*)d_in[2];
  const float* P_w   = (const float*)d_in[3];
  const float* P_b   = (const float*)d_in[4];
  const float* emb   = (const float*)d_in[5];
  const float* din_w = (const float*)d_in[6];
  const float* din_b = (const float*)d_in[7];
  const float* k0    = (const float*)d_in[8];
  const float* r0    = (const float*)d_in[9];
  const float* b0    = (const float*)d_in[10];
  const float* k1    = (const float*)d_in[11];
  const float* r1    = (const float*)d_in[12];
  const float* b1    = (const float*)d_in[13];
  float* out = (float*)d_out;

  char* base = (char*)d_ws;
  size_t off = 0;
  auto alloc = [&](size_t b) -> void* {
    void* p = base + off;
    off = (off + b + 255) & ~(size_t)255;
    return p;
  };
  float* xk0  = (float*)alloc(8192UL * 2048 * 4);   // 67 MB
  u16* encb   = (u16*)alloc(32UL * 512 * 512 * 2);
  u16* encT   = (u16*)alloc(32UL * 512 * 512 * 2);
  float* aTf  = (float*)alloc(32UL * 256 * 512 * 4);
  u16* aTb    = (u16*)alloc(32UL * 256 * 512 * 2);
  u16* pd     = (u16*)alloc(8192UL * 512 * 2);
  u16* wt_r0  = (u16*)alloc(2048UL * 512 * 2);
  u16* wt_k1  = (u16*)alloc(2048UL * 512 * 2);
  u16* wt_r1  = (u16*)alloc(2048UL * 512 * 2);
  u16* k0T    = (u16*)alloc(2048UL * 512 * 2);
  u16* PwT    = (u16*)alloc(512UL * 512 * 2);
  u16* dinwb  = (u16*)alloc(512UL * 512 * 2);
  u16* WfT    = (u16*)alloc(2048UL * 512 * 2);
  float* bfld = (float*)alloc(2048 * 4);
  u16* h0b    = (u16*)alloc(2UL * 32 * 512 * 2);
  u16* h1b    = (u16*)alloc(2UL * 32 * 512 * 2);
  int* slots  = (int*)alloc(192 * 32 * 4);          // 24 KB epoch slots

  conv_kernel<<<8192, 256, 0, stream>>>(enc, encb, 32L * 512 * 512);
  tconv_kernel<<<dim3(16, 16, 32), 256, 0, stream>>>(enc, encT, 512, 512, 262144, 262144);
  tconv_kernel<<<dim3(64, 16, 1), 256, 0, stream>>>(r0, wt_r0, 512, 2048, 0, 0);
  tconv_kernel<<<dim3(64, 16, 1), 256, 0, stream>>>(k1, wt_k1, 512, 2048, 0, 0);
  tconv_kernel<<<dim3(64, 16, 1), 256, 0, stream>>>(r1, wt_r1, 512, 2048, 0, 0);
  tconv_kernel<<<dim3(64, 16, 1), 256, 0, stream>>>(k0, k0T, 512, 2048, 0, 0);
  tconv_kernel<<<dim3(16, 16, 1), 256, 0, stream>>>(P_w, PwT, 512, 512, 0, 0);
  conv_kernel<<<256, 256, 0, stream>>>(din_w, dinwb, 512L * 512);

  // K1: py = emb[lw] @ P_w + P_b -> pd (bf16)
  gemm_bt_kernel<1, 0, true><<<dim3(4, 64, 1), 256, 0, stream>>>(
      nullptr, emb, PwT, nullptr, pd, P_b, lw, nullptr, 0,
      8192, 512, 512, 0, 0, 0, 0);
  // K5: WfT = (din_w @ k0)^T
  gemm_bt_kernel<0, 3, false><<<dim3(16, 4, 1), 256, 0, stream>>>(
      dinwb, nullptr, k0T, nullptr, WfT, nullptr, nullptr, nullptr, 0,
      512, 2048, 512, 0, 0, 0, 0);
  bfold_kernel<<<8, 256, 0, stream>>>(din_b, k0, b0, bfld);
  // K2: scores + mask
  gemm_bt_kernel<0, 2, false><<<dim3(4, 2, 32), 256, 0, stream>>>(
      pd, nullptr, encb, aTf, nullptr, nullptr, nullptr, mask, 256,
      256, 512, 512, 131072, 262144, 131072, 131072);
  softmax_kernel<<<2048, 256, 0, stream>>>(aTf, aTb);
  // K4: dec = softmax @ enc
  gemm_bt_kernel<0, 0, false><<<dim3(4, 2, 32), 256, 0, stream>>>(
      aTb, nullptr, encT, nullptr, pd, nullptr, nullptr, nullptr, 0,
      256, 512, 512, 131072, 262144, 131072, 0);
  // K6: xk0 = dec @ (din_w@k0) + folded bias
  gemm_bt_kernel<0, 1, true><<<dim3(16, 64, 1), 256, 0, stream>>>(
      pd, nullptr, WfT, xk0, nullptr, bfld, nullptr, nullptr, 0,
      8192, 2048, 512, 0, 0, 0, 0);

  hipMemsetAsync(slots, 0, 192 * 32 * 4, stream);
  lstm_kernel<<<192, 256, 0, stream>>>(wt_r0, wt_k1, wt_r1, xk0, b1, h0b, h1b, out, slots);
}